// Round 8
// baseline (163.119 us; speedup 1.0000x reference)
//
#include <hip/hip_runtime.h>
#include <math.h>

// EKF propagate: B=65536, nx=16, nz=8, nu=4, fp32.
//
// R12 = R6's 8-lane dual-row structure (best VALU/element: every uniform
// s_load feeds 2 chains) + R11's proven join cuts + PACKED FP32.
// Evidence: R11 (59.2us best) has VALUBusy 54% -> 32us chip VALU-busy of
// 59.5; nothing else saturated. gfx950 has v_pk_fma_f32 (packed fp32,
// gfx90a-lineage); R6's dual accumulator chains (rows r0/r1 share every
// operand: uniform A/C scalar, broadcast SI/tp^T scalar) are exact pk
// pairs. Expressed as ext_vector_type(2) float2 math -> backend emits
// v_pk_fma_f32, halving ~1200 math instr/wave to ~600. Benign failure:
// if not fused, identical scalar FMAs to current code (null, no loss).
// Also: phase-separated V and tp (compute->burst write, no SMEM<->DS
// lgkm mixing, R11-proven), TPB=128 + GS=308 -> 19712B -> 8 blocks/CU
// (finer residency granularity than R6's 4x256).

namespace {

typedef float v2f __attribute__((ext_vector_type(2)));

__device__ __forceinline__ v2f mk2(float a, float b) {
  v2f r; r.x = a; r.y = b; return r;
}

constexpr int LPE    = 8;            // lanes per element
constexpr int GROUPS = 16;           // elements per block
constexpr int TPB    = GROUPS * LPE; // 128 threads

// Per-group LDS layout (floats). Overlays by liveness:
//  [0,256)   VT : V^T 16x16                           [V .. W]
//  [0,128)   TPT: tp^T 8x16  (overlay)                [tp .. final]
//  [128,192) SI : S^-1 rows 8x8 (overlay VT[128:192]) [post-GJ .. K]
//  [256,272) mubar[16]; [272,288) d[16]; [288,296) h[8]; [296,304) dh[8]
constexpr int O_VT  = 0;
constexpr int O_TPT = 0;
constexpr int O_SI  = 128;
constexpr int O_MU  = 256;
constexpr int O_D   = 272;
constexpr int O_H   = 288;
constexpr int O_DH  = 296;
constexpr int GS    = 308;  // %32==20 -> the 8 group bases of a wave land on
                            // 8 distinct bank offsets (broadcasts conflict-
                            // free); %4==0 float4-aligned. 16*308*4=19712B.

__device__ __forceinline__ float dot4(float4 a, float4 b) {
  return a.x*b.x + a.y*b.y + a.z*b.z + a.w*b.w;
}

// tanh(x) = 1 - 2/(e^{2x}+1); v_exp_f32 + v_rcp_f32. abs err ~1e-7.
__device__ __forceinline__ float tanh_fast(float x) {
  float e = __expf(2.0f * x);
  return 1.0f - 2.0f * __builtin_amdgcn_rcpf(e + 1.0f);
}

// ds_swizzle BitMode: src_lane = ((lane & 0x18) | P) -> broadcast lane P of
// each aligned 8-lane group (offset imm must be a literal -> macro).
#define SWZF(v, imm) __int_as_float(__builtin_amdgcn_ds_swizzle(__float_as_int(v), (imm)))

// One Gauss-Jordan step for pivot P (literal). Rows in registers:
// s8[8] (S row t), x8[8] (inverse row t). Invariants at entry to step P:
//   s8[j] maintained for j>=P; x8[j] maintained for j<P; x8[j>=P]=delta_tj;
//   pivot row's x8[P]==1. f-trick: for t==P, f=ps[P]-1 makes
//   s8[j]-f*(ps[j]*rp) == ps[j]*rp (normalized pivot row) -- branchless.
#define GJ_STEP(P)                                                         \
  {                                                                        \
    float ps[8], px[8];                                                    \
    _Pragma("unroll")                                                      \
    for (int j = 0; j < 8; j++) {                                          \
      if (j >= (P)) ps[j] = SWZF(s8[j], (((P) << 5) | 0x18));              \
      else          px[j] = SWZF(x8[j], (((P) << 5) | 0x18));              \
    }                                                                      \
    const float rp = __builtin_amdgcn_rcpf(ps[(P)]);                       \
    const float f  = (t == (P)) ? (ps[(P)] - 1.0f) : s8[(P)];              \
    _Pragma("unroll")                                                      \
    for (int j = 0; j < 8; j++) {                                          \
      if (j > (P))      s8[j] -= f * (ps[j] * rp);                         \
      else if (j < (P)) x8[j] -= f * (px[j] * rp);                         \
    }                                                                      \
    x8[(P)] -= f * rp;                                                     \
  }

__global__ __launch_bounds__(TPB)    // no min-waves clause (R3 spill lesson)
void ekf_kernel(const float* __restrict__ mu_prev,
                const float* __restrict__ Sig_prev,
                const float* __restrict__ U,
                const float* __restrict__ Z,
                const float* __restrict__ A,
                const float* __restrict__ Bm,
                const float* __restrict__ C,
                const float* __restrict__ Q,
                const float* __restrict__ R,
                float* __restrict__ mu_out,
                float* __restrict__ sig_out,
                int Btot)
{
  __shared__ float lds[GS * GROUPS];   // 19712 B -> 8 blocks/CU
  const int tid = threadIdx.x;
  const int g = tid >> 3;              // group (element) within block
  const int t = tid & 7;               // lane within group
  int e = blockIdx.x * GROUPS + g;
  if (e >= Btot) e = Btot - 1;         // clamp; duplicate-write benign
  float* L = lds + g * GS;
  const int r0 = t, r1 = t + 8;        // owned matrix rows

  // ---- load Sigma rows r0,r1 as packed pairs sigp[k] = {S[r0,k],S[r1,k]} ----
  v2f sigp[16];
  {
    const float4* s0 = (const float4*)(Sig_prev + (size_t)e * 256 + r0 * 16);
    const float4* s1 = (const float4*)(Sig_prev + (size_t)e * 256 + r1 * 16);
    #pragma unroll
    for (int c = 0; c < 4; c++) {
      float4 v0 = s0[c], v1 = s1[c];
      sigp[4*c+0] = mk2(v0.x, v1.x);
      sigp[4*c+1] = mk2(v0.y, v1.y);
      sigp[4*c+2] = mk2(v0.z, v1.z);
      sigp[4*c+3] = mk2(v0.w, v1.w);
    }
  }

  // ---- mu_bar rows r0,r1 (dual scalar chains; per-lane A rows via L1) ----
  float mubar0, mubar1, d0loc, d1loc;
  {
    const float4* mr = (const float4*)(mu_prev + (size_t)e * 16);
    float4 m0 = mr[0], m1 = mr[1], m2 = mr[2], m3 = mr[3];
    const float4* a0 = (const float4*)(A + r0 * 16);
    const float4* a1 = (const float4*)(A + r1 * 16);
    float p0 = dot4(a0[0],m0)+dot4(a0[1],m1)+dot4(a0[2],m2)+dot4(a0[3],m3);
    float p1 = dot4(a1[0],m0)+dot4(a1[1],m1)+dot4(a1[2],m2)+dot4(a1[3],m3);
    float4 u4 = *(const float4*)(U + (size_t)e * 4);
    p0 += dot4(*(const float4*)(Bm + r0 * 4), u4);
    p1 += dot4(*(const float4*)(Bm + r1 * 4), u4);
    mubar0 = tanh_fast(p0); d0loc = 1.0f - mubar0 * mubar0;
    mubar1 = tanh_fast(p1); d1loc = 1.0f - mubar1 * mubar1;
  }
  L[O_MU + r0] = mubar0; L[O_MU + r1] = mubar1;
  L[O_D  + r0] = d0loc;  L[O_D  + r1] = d1loc;
  __builtin_amdgcn_wave_barrier();

  // ---- h[t], dh[t]; keep C row t in regs for S-build ----
  float4 ct0, ct1, ct2, ct3;
  float dhl;
  {
    const float4* cr = (const float4*)(C + t * 16);
    ct0 = cr[0]; ct1 = cr[1]; ct2 = cr[2]; ct3 = cr[3];
    const float4* mb = (const float4*)(L + O_MU);
    float ph = dot4(ct0,mb[0])+dot4(ct1,mb[1])+dot4(ct2,mb[2])+dot4(ct3,mb[3]);
    float hb = tanh_fast(ph); dhl = 1.0f - hb * hb;
    L[O_H + t] = hb; L[O_DH + t] = dhl;
  }
  __builtin_amdgcn_wave_barrier();
  float dh[8];
  {
    float4 v0 = *(const float4*)(L + O_DH);
    float4 v1 = *(const float4*)(L + O_DH + 4);
    dh[0]=v0.x; dh[1]=v0.y; dh[2]=v0.z; dh[3]=v0.w;
    dh[4]=v1.x; dh[5]=v1.y; dh[6]=v1.z; dh[7]=v1.w;
  }

  // ---- V = Sig * A^T rows r0,r1: PACKED + PHASE-SEPARATED (all 16 pk
  //      dots into regs, then burst of 32 ds_writes) ----
  v2f vv[16];
  #pragma unroll
  for (int j = 0; j < 16; j++) {
    v2f acc = {0.f, 0.f};
    #pragma unroll
    for (int k = 0; k < 16; k++) {
      const float a = A[j*16 + k];            // uniform -> s_load, splat
      acc += sigp[k] * a;                     // v_pk_fma_f32
    }
    vv[j] = acc;
  }
  #pragma unroll
  for (int j = 0; j < 16; j++) {
    L[O_VT + j*16 + r0] = vv[j].x;            // V^T scatter
    L[O_VT + j*16 + r1] = vv[j].y;
  }
  __builtin_amdgcn_wave_barrier();

  // ---- packed V columns r0,r1 (contiguous VT rows) ----
  v2f vcp[16];
  {
    const float4* p0 = (const float4*)(L + O_VT + r0 * 16);
    const float4* p1 = (const float4*)(L + O_VT + r1 * 16);
    #pragma unroll
    for (int c = 0; c < 4; c++) {
      float4 x0 = p0[c], x1 = p1[c];
      vcp[4*c+0] = mk2(x0.x, x1.x);
      vcp[4*c+1] = mk2(x0.y, x1.y);
      vcp[4*c+2] = mk2(x0.z, x1.z);
      vcp[4*c+3] = mk2(x0.w, x1.w);
    }
  }
  __builtin_amdgcn_wave_barrier();            // VT dead; TPT may overlay

  // ---- W rows (W = A*V, sym) PACKED, fused with Sig_bar:
  //      sbp[i] = {R[r0,i],R[r1,i]} + {d0,d1}*W*d[i] ----
  v2f sbp[16];
  {
    const float4* rr0 = (const float4*)(R + r0 * 16);
    const float4* rr1 = (const float4*)(R + r1 * 16);
    const float4* dv  = (const float4*)(L + O_D);
    const v2f dpair = mk2(d0loc, d1loc);
    #pragma unroll
    for (int c = 0; c < 4; c++) {
      float4 ra = rr0[c], rb = rr1[c], dd = dv[c];
      #pragma unroll
      for (int q = 0; q < 4; q++) {
        const int i = 4*c + q;
        v2f acc = {0.f, 0.f};
        #pragma unroll
        for (int k = 0; k < 16; k++) {
          const float a = A[i*16 + k];        // uniform -> s_load, splat
          acc += vcp[k] * a;                  // v_pk_fma_f32
        }
        const float rx = (q==0)?ra.x:(q==1)?ra.y:(q==2)?ra.z:ra.w;
        const float ry = (q==0)?rb.x:(q==1)?rb.y:(q==2)?rb.z:rb.w;
        const float dq = (q==0)?dd.x:(q==1)?dd.y:(q==2)?dd.z:dd.w;
        sbp[i] = mk2(rx, ry) + dpair * acc * dq;
      }
    }
  }

  // ---- tp rows PACKED: tpp[m] = {tp[r0,m],tp[r1,m]}; burst tp^T writes ----
  v2f tpp[8];
  #pragma unroll
  for (int m = 0; m < 8; m++) {
    v2f acc = {0.f, 0.f};
    #pragma unroll
    for (int k = 0; k < 16; k++) {
      const float c = C[m*16 + k];            // uniform -> s_load, splat
      acc += sbp[k] * c;                      // v_pk_fma_f32
    }
    tpp[m] = acc * dh[m];
  }
  #pragma unroll
  for (int m = 0; m < 8; m++) {
    L[O_TPT + m*16 + r0] = tpp[m].x;
    L[O_TPT + m*16 + r1] = tpp[m].y;
  }
  __builtin_amdgcn_wave_barrier();

  // ---- S row t = dh_t*(C[t,:] @ tp) + Q[t,:] (all 8 lanes active;
  //      packed over adjacent k-pairs: VGPRxVGPR pk) ----
  float s8[8];
  {
    float4 q0 = *(const float4*)(Q + t * 8);
    float4 q1 = *(const float4*)(Q + t * 8 + 4);
    float qv[8] = {q0.x,q0.y,q0.z,q0.w,q1.x,q1.y,q1.z,q1.w};
    #pragma unroll
    for (int m = 0; m < 8; m++) {
      const float4* tr = (const float4*)(L + O_TPT + m * 16);  // broadcast
      float4 t0 = tr[0], t1 = tr[1], t2 = tr[2], t3 = tr[3];
      v2f acc = {0.f, 0.f};
      acc += mk2(ct0.x, ct0.y) * mk2(t0.x, t0.y);
      acc += mk2(ct0.z, ct0.w) * mk2(t0.z, t0.w);
      acc += mk2(ct1.x, ct1.y) * mk2(t1.x, t1.y);
      acc += mk2(ct1.z, ct1.w) * mk2(t1.z, t1.w);
      acc += mk2(ct2.x, ct2.y) * mk2(t2.x, t2.y);
      acc += mk2(ct2.z, ct2.w) * mk2(t2.z, t2.w);
      acc += mk2(ct3.x, ct3.y) * mk2(t3.x, t3.y);
      acc += mk2(ct3.z, ct3.w) * mk2(t3.z, t3.w);
      s8[m] = (acc.x + acc.y) * dhl + qv[m];
    }
  }

  // ---- Gauss-Jordan inverse of S via swizzle broadcasts (no LDS round
  //      trips, full wave active; S SPD -> no pivoting) ----
  float x8[8];
  #pragma unroll
  for (int j = 0; j < 8; j++) x8[j] = (j == t) ? 1.0f : 0.0f;
  GJ_STEP(0) GJ_STEP(1) GJ_STEP(2) GJ_STEP(3)
  GJ_STEP(4) GJ_STEP(5) GJ_STEP(6) GJ_STEP(7)

  // ---- stash S^-1 rows ----
  *((float4*)(L + O_SI + t*8 + 0)) = make_float4(x8[0], x8[1], x8[2], x8[3]);
  *((float4*)(L + O_SI + t*8 + 4)) = make_float4(x8[4], x8[5], x8[6], x8[7]);
  __builtin_amdgcn_wave_barrier();

  // ---- K rows PACKED: kp[j] = {K[r0,j],K[r1,j]} += tpp[m]*SI[m][j] ----
  v2f kp[8] = {{0.f,0.f},{0.f,0.f},{0.f,0.f},{0.f,0.f},
               {0.f,0.f},{0.f,0.f},{0.f,0.f},{0.f,0.f}};
  #pragma unroll
  for (int m = 0; m < 8; m++) {
    float4 a = *(const float4*)(L + O_SI + m*8 + 0);   // broadcast
    float4 b = *(const float4*)(L + O_SI + m*8 + 4);
    const v2f f = tpp[m];
    kp[0] += f * a.x; kp[1] += f * a.y; kp[2] += f * a.z; kp[3] += f * a.w;
    kp[4] += f * b.x; kp[5] += f * b.y; kp[6] += f * b.z; kp[7] += f * b.w;
  }

  // ---- mu rows PACKED ----
  {
    float4 z0 = *(const float4*)(Z + (size_t)e * 8);
    float4 z1 = *(const float4*)(Z + (size_t)e * 8 + 4);
    float4 h0 = *(const float4*)(L + O_H);
    float4 h1 = *(const float4*)(L + O_H + 4);
    float i0=z0.x-h0.x, i1=z0.y-h0.y, i2=z0.z-h0.z, i3=z0.w-h0.w;
    float i4=z1.x-h1.x, i5=z1.y-h1.y, i6=z1.z-h1.z, i7=z1.w-h1.w;
    v2f mup = mk2(mubar0, mubar1);
    mup += kp[0]*i0; mup += kp[1]*i1; mup += kp[2]*i2; mup += kp[3]*i3;
    mup += kp[4]*i4; mup += kp[5]*i5; mup += kp[6]*i6; mup += kp[7]*i7;
    mu_out[(size_t)e * 16 + r0] = mup.x;
    mu_out[(size_t)e * 16 + r1] = mup.y;
  }

  // ---- Sig_now rows PACKED = Sig_bar - K tp^T  (K S = tp exactly in
  //      real arithmetic -> equals Joseph form; fp delta ~1e-6) ----
  #pragma unroll
  for (int m = 0; m < 8; m++) {
    const float4* tr = (const float4*)(L + O_TPT + m * 16);  // broadcast
    float4 t0 = tr[0], t1 = tr[1], t2 = tr[2], t3 = tr[3];
    const v2f km = kp[m];
    sbp[0]  -= km * t0.x; sbp[1]  -= km * t0.y;
    sbp[2]  -= km * t0.z; sbp[3]  -= km * t0.w;
    sbp[4]  -= km * t1.x; sbp[5]  -= km * t1.y;
    sbp[6]  -= km * t1.z; sbp[7]  -= km * t1.w;
    sbp[8]  -= km * t2.x; sbp[9]  -= km * t2.y;
    sbp[10] -= km * t2.z; sbp[11] -= km * t2.w;
    sbp[12] -= km * t3.x; sbp[13] -= km * t3.y;
    sbp[14] -= km * t3.z; sbp[15] -= km * t3.w;
  }
  {
    float4* o0 = (float4*)(sig_out + (size_t)e * 256 + r0 * 16);
    float4* o1 = (float4*)(sig_out + (size_t)e * 256 + r1 * 16);
    o0[0] = make_float4(sbp[0].x,  sbp[1].x,  sbp[2].x,  sbp[3].x);
    o0[1] = make_float4(sbp[4].x,  sbp[5].x,  sbp[6].x,  sbp[7].x);
    o0[2] = make_float4(sbp[8].x,  sbp[9].x,  sbp[10].x, sbp[11].x);
    o0[3] = make_float4(sbp[12].x, sbp[13].x, sbp[14].x, sbp[15].x);
    o1[0] = make_float4(sbp[0].y,  sbp[1].y,  sbp[2].y,  sbp[3].y);
    o1[1] = make_float4(sbp[4].y,  sbp[5].y,  sbp[6].y,  sbp[7].y);
    o1[2] = make_float4(sbp[8].y,  sbp[9].y,  sbp[10].y, sbp[11].y);
    o1[3] = make_float4(sbp[12].y, sbp[13].y, sbp[14].y, sbp[15].y);
  }
}

} // namespace

extern "C" void kernel_launch(void* const* d_in, const int* in_sizes, int n_in,
                              void* d_out, int out_size, void* d_ws, size_t ws_size,
                              hipStream_t stream)
{
  const float* mu_prev = (const float*)d_in[0];
  const float* Sigma   = (const float*)d_in[1];
  const float* u       = (const float*)d_in[2];
  const float* z       = (const float*)d_in[3];
  const float* A       = (const float*)d_in[4];
  const float* Bm      = (const float*)d_in[5];
  const float* C       = (const float*)d_in[6];
  const float* Q       = (const float*)d_in[7];
  const float* R       = (const float*)d_in[8];

  const int Btot = in_sizes[0] / 16;                 // B = 65536
  float* mu_out  = (float*)d_out;
  float* sig_out = (float*)d_out + (size_t)Btot * 16;

  const int grid = (Btot + GROUPS - 1) / GROUPS;     // 4096 blocks x 128 thr
  ekf_kernel<<<grid, TPB, 0, stream>>>(mu_prev, Sigma, u, z, A, Bm, C, Q, R,
                                       mu_out, sig_out, Btot);
}